// Round 7
// baseline (80.168 us; speedup 1.0000x reference)
//
#include <hip/hip_runtime.h>

#define FC  75                 // K*K*C floats per pixel
#define GP  64                 // pixels per block = lanes per wave
#define SLABF 4864             // 1216 float4: 1200 data + 16 pad for clamp tail

typedef float f32x4 __attribute__((ext_vector_type(4), aligned(4)));

// 16384 blocks x 64 threads: one wave = one 64-pixel group (R6 structure).
// Stage: 19x width-16 global_load_lds -> vmcnt(0) -> compute. 8 blocks/CU.
// R7 change: img loads vectorized — each lane's 5x5x3 neighborhood is 15
// contiguous floats per row -> 4x float4 per row (20 VMEM/block vs 75),
// ~4x fewer L1 line touches in the compute phase.

__global__ __launch_bounds__(64, 2)
void convolve_kernel(const float* __restrict__ img,
                     const float* __restrict__ filts,
                     float* __restrict__ out)
{
    __shared__ float slab[SLABF];

    const int lane = threadIdx.x;          // 0..63

    // bijective XCD-chunked swizzle (16384 % 8 == 0)
    const int g = ((int)blockIdx.x & 7) * 2048 + ((int)blockIdx.x >> 3);

    // ---- stage this group's 4800 filts floats (1200 float4) into LDS ----
    {
        const f32x4* src4 = (const f32x4*)(filts + (size_t)g * (GP * FC));
        #pragma unroll
        for (int j = 0; j < 19; ++j) {
            int idx4 = j * 64 + lane;
            idx4 = idx4 > 1199 ? 1199 : idx4;   // clamp tail (lands in pad)
            __builtin_amdgcn_global_load_lds(
                (const __attribute__((address_space(1))) void*)(src4 + idx4),
                (__attribute__((address_space(3))) void*)(slab + j * 256),
                16, 0, 0);
        }
    }
    asm volatile("s_waitcnt vmcnt(0)" ::: "memory");
    __builtin_amdgcn_sched_barrier(0);      // rule #18: ds_reads stay below wait

    // ---- compute: one pixel per lane ----
    const int p  = g * GP + lane;           // 64 consecutive pixels, same row
    const int b  = p >> 18;                 // / (512*512)
    const int hw = p & ((1 << 18) - 1);
    const int h  = hw >> 9;
    const int w  = hw & 511;

    const float* fp   = slab + lane * FC;   // stride 75 dwords -> 2/bank, free
    const float* imgb = img + (size_t)b * (512u * 512u * 3u);

    // interior: the 16-float row window [(w-2)*3, (w-2)*3+16) stays inside
    // the row (w=509 would touch float 1536 -> next row/page; exclude it)
    const bool interior = (w >= 2) && (w <= 508);

    float a0 = 0.f, a1 = 0.f, a2 = 0.f;     // 3 chains vs FMA dep latency
    #pragma unroll
    for (int di = 0; di < 5; ++di) {
        const int hh = h + di - 2;
        if ((unsigned)hh < 512u) {           // wave-uniform (h uniform per group)
            const float* row = imgb + (size_t)hh * 1536;
            if (interior) {
                const float* q  = row + (w - 2) * 3;   // 15 floats used of 16
                const f32x4 v0 = *(const f32x4*)(q);
                const f32x4 v1 = *(const f32x4*)(q + 4);
                const f32x4 v2 = *(const f32x4*)(q + 8);
                const f32x4 v3 = *(const f32x4*)(q + 12);
                const float* fr = fp + di * 15;
                a0 += v0.x * fr[0];  a1 += v0.y * fr[1];  a2 += v0.z * fr[2];
                a0 += v0.w * fr[3];  a1 += v1.x * fr[4];  a2 += v1.y * fr[5];
                a0 += v1.z * fr[6];  a1 += v1.w * fr[7];  a2 += v2.x * fr[8];
                a0 += v2.y * fr[9];  a1 += v2.z * fr[10]; a2 += v2.w * fr[11];
                a0 += v3.x * fr[12]; a1 += v3.y * fr[13]; a2 += v3.z * fr[14];
            } else {                          // 2-3 lanes in 2 of 8 waves
                #pragma unroll
                for (int dj = 0; dj < 5; ++dj) {
                    const int ww = w + dj - 2;
                    if ((unsigned)ww < 512u) {
                        const float* px = row + ww * 3;
                        const float* fr = fp + (di * 5 + dj) * 3;
                        a0 += px[0] * fr[0];
                        a1 += px[1] * fr[1];
                        a2 += px[2] * fr[2];
                    }
                }
            }
        }
    }
    out[p] = a0 + a1 + a2;
}

extern "C" void kernel_launch(void* const* d_in, const int* in_sizes, int n_in,
                              void* d_out, int out_size, void* d_ws, size_t ws_size,
                              hipStream_t stream)
{
    const float* img   = (const float*)d_in[0];   // [4,512,512,3]  f32
    const float* filts = (const float*)d_in[1];   // [4,512,512,75] f32
    float* out         = (float*)d_out;           // [4,512,512]    f32

    // 1,048,576 pixels / 64 per block = 16384 blocks of 64 threads
    convolve_kernel<<<16384, 64, 0, stream>>>(img, filts, out);
}

// Round 8
// 78.105 us; speedup vs baseline: 1.0264x; 1.0264x over previous
//
#include <hip/hip_runtime.h>

#define FC    75               // K*K*C floats per pixel
#define GP    64               // pixels per group = lanes per wave
#define SLABF 4864             // 1216 float4: 1200 data + 16 pad for clamp tail
#define GPB   16               // groups per block

typedef float f32x4 __attribute__((ext_vector_type(4), aligned(4)));

// 1024 persistent blocks x 64 threads (1 wave), 16 groups each, 4 blocks/CU.
// Ordered depth-2 pipeline per iteration:
//   img(k) -> regs   [issued FIRST]
//   stage(k+1) -> other slab (19x width-16 global_load_lds)
//   s_waitcnt vmcnt(19): in-order retirement => img(k)+slab(k) landed,
//                        the 19 prefetch loads keep flying through compute.
// Every wave holds >=19KB outstanding at all times -> no dead HBM windows.

__global__ __launch_bounds__(64, 1)
void convolve_kernel(const float* __restrict__ img,
                     const float* __restrict__ filts,
                     float* __restrict__ out)
{
    __shared__ float slabA[SLABF];
    __shared__ float slabB[SLABF];

    const int lane = threadIdx.x;          // 0..63

    // bijective XCD-chunked swizzle (1024 % 8 == 0): XCD x -> contiguous
    // 128-block chunk = 128K consecutive pixels (img slice ~1.6MB in its L2).
    const int wgid = ((int)blockIdx.x & 7) * 128 + ((int)blockIdx.x >> 3);
    const int g0   = wgid * GPB;

    // stage one group's 4800 filts floats (1200 float4) into a slab
    auto stage = [&](float* slab, int g) {
        const f32x4* src4 = (const f32x4*)(filts + (size_t)g * (GP * FC));
        #pragma unroll
        for (int j = 0; j < 19; ++j) {
            int idx4 = j * 64 + lane;
            idx4 = idx4 > 1199 ? 1199 : idx4;   // clamp tail (lands in pad)
            __builtin_amdgcn_global_load_lds(
                (const __attribute__((address_space(1))) void*)(src4 + idx4),
                (__attribute__((address_space(3))) void*)(slab + j * 256),
                16, 0, 0);
        }
    };

    stage(slabA, g0);                       // prologue: fill first slab
    float* cur = slabA;
    float* nxt = slabB;

    #pragma unroll 1
    for (int k = 0; k < GPB; ++k) {
        const int g  = g0 + k;
        const int p  = g * GP + lane;       // 64 consecutive pixels, same row
        const int b  = p >> 18;
        const int hw = p & ((1 << 18) - 1);
        const int h  = hw >> 9;
        const int w  = hw & 511;
        const float* imgb = img + (size_t)b * (512u * 512u * 3u);

        // ---- 1. img(k) -> regs, BEFORE the prefetch (in-order vmcnt) ----
        f32x4 v[5][4];
        #pragma unroll
        for (int di = 0; di < 5; ++di)
            #pragma unroll
            for (int jj = 0; jj < 4; ++jj)
                v[di][jj] = (f32x4)0.f;

        const int gm8 = g & 7;
        if (gm8 != 0 && gm8 != 7) {
            // fully w-interior group: 4x f32x4 per valid row (15 of 16 used)
            const float* q0 = imgb + (w - 2) * 3;
            #pragma unroll
            for (int di = 0; di < 5; ++di) {
                const int hh = h + di - 2;
                if ((unsigned)hh < 512u) {  // wave-uniform
                    const float* q = q0 + (size_t)hh * 1536;
                    v[di][0] = *(const f32x4*)(q);
                    v[di][1] = *(const f32x4*)(q + 4);
                    v[di][2] = *(const f32x4*)(q + 8);
                    v[di][3] = *(const f32x4*)(q + 12);
                }
            }
        } else {
            // row-edge group: guarded scalar loads into zeroed regs
            #pragma unroll
            for (int di = 0; di < 5; ++di) {
                const int hh = h + di - 2;
                if ((unsigned)hh < 512u) {
                    const float* row = imgb + (size_t)hh * 1536;
                    #pragma unroll
                    for (int dj = 0; dj < 5; ++dj) {
                        const int ww = w + dj - 2;
                        if ((unsigned)ww < 512u) {
                            const float* px = row + ww * 3;
                            #pragma unroll
                            for (int c = 0; c < 3; ++c) {
                                const int idx = dj * 3 + c;
                                v[di][idx >> 2][idx & 3] = px[c];
                            }
                        }
                    }
                }
            }
        }
        __builtin_amdgcn_sched_barrier(0);  // img issue stays ABOVE prefetch

        // ---- 2. prefetch filts(k+1) into the other slab ----
        if (k + 1 < GPB) {
            stage(nxt, g + 1);
            // ---- 3. wait: all but the 19 newest (the prefetch) retired ----
            asm volatile("s_waitcnt vmcnt(19)" ::: "memory");
        } else {
            asm volatile("s_waitcnt vmcnt(0)" ::: "memory");
        }
        __builtin_amdgcn_sched_barrier(0);  // rule #18: ds_reads stay below

        // ---- 4. compute group k: LDS filts x reg img ----
        const float* fp = cur + lane * FC;  // stride 75 dw -> 2/bank, free
        float a0 = 0.f, a1 = 0.f, a2 = 0.f;
        #pragma unroll
        for (int di = 0; di < 5; ++di) {
            const float* fr = fp + di * 15;
            a0 += v[di][0].x * fr[0];  a1 += v[di][0].y * fr[1];  a2 += v[di][0].z * fr[2];
            a0 += v[di][0].w * fr[3];  a1 += v[di][1].x * fr[4];  a2 += v[di][1].y * fr[5];
            a0 += v[di][1].z * fr[6];  a1 += v[di][1].w * fr[7];  a2 += v[di][2].x * fr[8];
            a0 += v[di][2].y * fr[9];  a1 += v[di][2].z * fr[10]; a2 += v[di][2].w * fr[11];
            a0 += v[di][3].x * fr[12]; a1 += v[di][3].y * fr[13]; a2 += v[di][3].z * fr[14];
        }
        out[p] = a0 + a1 + a2;

        float* t = cur; cur = nxt; nxt = t;
    }
}

extern "C" void kernel_launch(void* const* d_in, const int* in_sizes, int n_in,
                              void* d_out, int out_size, void* d_ws, size_t ws_size,
                              hipStream_t stream)
{
    const float* img   = (const float*)d_in[0];   // [4,512,512,3]  f32
    const float* filts = (const float*)d_in[1];   // [4,512,512,75] f32
    float* out         = (float*)d_out;           // [4,512,512]    f32

    // 16384 groups / 16 per block = 1024 blocks of 64 threads (4/CU by LDS)
    convolve_kernel<<<1024, 64, 0, stream>>>(img, filts, out);
}